// Round 7
// baseline (242.671 us; speedup 1.0000x reference)
//
#include <hip/hip_runtime.h>
#include <cstdint>
#include <cstddef>

typedef short bf16x8 __attribute__((ext_vector_type(8)));
typedef float f32x4 __attribute__((ext_vector_type(4)));

#define EPS 1e-3f

__device__ __forceinline__ short f32_to_bf16s(float f) {
    union { float f; uint32_t u; } v; v.f = f;
    return (short)((v.u + 0x7FFFu + ((v.u >> 16) & 1u)) >> 16);
}

// K0: wt[kp][ci] = bf16(W[ci][kp]) (192x64); at[w][k] = bf16(A[p][v][w]) (32x96, k=p*25+v, zero-padded)
__global__ __launch_bounds__(256) void prep_kernel(const float* __restrict__ A,
                                                   const float* __restrict__ W,
                                                   unsigned short* __restrict__ wt,
                                                   unsigned short* __restrict__ at) {
    int idx = blockIdx.x * 256 + threadIdx.x;
    if (idx < 12288) {
        int kp = idx >> 6, ci = idx & 63;
        wt[idx] = (unsigned short)f32_to_bf16s(W[ci * 192 + kp]);
    } else {
        int j = idx - 12288;
        if (j < 3072) {
            int w = j / 96, k = j - w * 96;
            float val = 0.f;
            if (w < 25 && k < 75) {
                int p = k / 25, v = k - p * 25;
                val = A[(p * 25 + v) * 25 + w];
            }
            at[j] = (unsigned short)f32_to_bf16s(val);
        }
    }
}

// Mega: block = (l-chunk of 8, n), 512 threads; wave wv owns l = l0+wv end-to-end.
// LDS ALIASED: smem = xwL[8 qs][207 cols][8] (13248 sh) until b1 loaded,
//              then Ys[128][104] (13312 sh). Two barriers total.
// 27.1 KB LDS -> 4 blocks/CU (thread-capped) = 32 waves/CU.
__global__ __launch_bounds__(512, 8) void mega_kernel(
    const float* __restrict__ x,
    const unsigned short* __restrict__ wt,
    const unsigned short* __restrict__ at,
    const float* __restrict__ gamma, const float* __restrict__ beta,
    const float* __restrict__ mean, const float* __restrict__ var,
    float* __restrict__ out) {
    const int ch = blockIdx.x, n = blockIdx.y;
    const int l0 = ch * 8;
    const int tid = threadIdx.x;
    const int wv = tid >> 6, lane = tid & 63, q = lane >> 4, lcol = lane & 15;

    __shared__ __align__(16) short smem[13312];   // xwL (13248) then Ys (13312)
    __shared__ float scs[64], shs[64];

    // b2 fragments (at, L2-resident) + BN constants — prefetched before phase 1
    bf16x8 b2[2][3];
    #pragma unroll
    for (int nt = 0; nt < 2; ++nt)
        #pragma unroll
        for (int s = 0; s < 3; ++s)
            b2[nt][s] = *(const bf16x8*)(at + (size_t)(nt * 16 + lcol) * 96 + 32 * s + 8 * q);
    if (tid < 64) {
        float sc = gamma[tid] * rsqrtf(var[tid] + EPS);
        scs[tid] = sc;
        shs[tid] = beta[tid] - mean[tid] * sc;
    }

    // Phase 1: per-(ci,v) running 9-window over l = l0..l0+7 -> xwL (bf16)
    #pragma unroll 1
    for (int rep = 0; rep < 4; ++rep) {
        int cidx = tid + rep * 512;
        if (cidx < 1600) {
            int ci = cidx / 25, v = cidx - ci * 25;
            const float* xp = x + (size_t)(n * 64 + ci) * 7500 + v;
            float vals[16];
            #pragma unroll
            for (int i = 0; i < 16; ++i) {
                int l = l0 - 8 + i;
                vals[i] = (l >= 0 && l < 300) ? xp[l * 25] : 0.f;
            }
            float run = vals[0] + vals[1] + vals[2] + vals[3]
                      + vals[4] + vals[5] + vals[6] + vals[7];
            short* wb = &smem[(ci >> 3) * 1656 + (ci & 7)];
            #pragma unroll
            for (int j = 0; j < 8; ++j) {
                run += vals[j + 8];
                wb[(j * 25 + v) * 8] = f32_to_bf16s(run);
                run -= vals[j];
            }
        }
    }
    __syncthreads();   // barrier 1: xwL ready

    // b1 fragments: B[k=ci][col], cols wv*25 + nt*16 + lcol (<=206; cols>=200 are
    // stale-but-finite garbage whose D-columns map to w>=25 and are never stored)
    bf16x8 b1[2][2];
    #pragma unroll
    for (int nt = 0; nt < 2; ++nt) {
        int col = wv * 25 + nt * 16 + lcol;
        #pragma unroll
        for (int s = 0; s < 2; ++s)
            b1[nt][s] = *(const bf16x8*)&smem[(4 * s + q) * 1656 + col * 8];
    }
    __syncthreads();   // barrier 2: all xwL reads done; smem becomes Ys

    // Zero own Ys slab pad cols [72,104): wave-private from here on.
    #pragma unroll
    for (int i = lane; i < 512; i += 64) {
        int r = i >> 5, cc = 72 + (i & 31);
        smem[(wv * 16 + r) * 104 + cc] = 0;
    }

    const int lg = l0 + wv;
    const size_t outrow = ((size_t)n * 64 * 300 + lg) * 25;   // + c*7500 + w

    #pragma unroll 1
    for (int g = 0; g < 4; ++g) {
        // a1 fragments for this c-group (wt, L1/L2-resident)
        bf16x8 a1[3][2];
        #pragma unroll
        for (int mt = 0; mt < 3; ++mt)
            #pragma unroll
            for (int s = 0; s < 2; ++s)
                a1[mt][s] = *(const bf16x8*)(wt + (size_t)(g * 48 + mt * 16 + lcol) * 64 + 32 * s + 8 * q);

        // GEMM1: M=48 (kp of group g), N=32 (own l, v+pad), K=64
        f32x4 acc[3][2];
        #pragma unroll
        for (int mt = 0; mt < 3; ++mt)
            #pragma unroll
            for (int nt = 0; nt < 2; ++nt) acc[mt][nt] = (f32x4){0.f, 0.f, 0.f, 0.f};
        #pragma unroll
        for (int s = 0; s < 2; ++s)
            #pragma unroll
            for (int mt = 0; mt < 3; ++mt) {
                bf16x8 av = a1[mt][s];
                #pragma unroll
                for (int nt = 0; nt < 2; ++nt)
                    acc[mt][nt] = __builtin_amdgcn_mfma_f32_16x16x32_bf16(av, b1[nt][s], acc[mt][nt], 0, 0, 0);
            }

        // Residual prefetch (L2-hot: same rows fetched by phase 1 of this block)
        float res[2][4];
        #pragma unroll
        for (int nt = 0; nt < 2; ++nt) {
            int w = nt * 16 + lcol;
            bool val = (w < 25) && (lg < 300);
            #pragma unroll
            for (int r = 0; r < 4; ++r) {
                int c = g * 16 + 4 * q + r;
                res[nt][r] = val ? x[outrow + (size_t)c * 7500 + w] : 0.f;
            }
        }

        // Stage D -> own Ys slab rows (wv*16+cl), col 25p+v   (wave-private, no barrier)
        #pragma unroll
        for (int mt = 0; mt < 3; ++mt)
            #pragma unroll
            for (int nt = 0; nt < 2; ++nt) {
                int v = nt * 16 + lcol;
                if (v < 25) {
                    #pragma unroll
                    for (int r = 0; r < 4; ++r) {
                        int kpl = mt * 16 + 4 * q + r;
                        int cl = kpl / 3, p = kpl - 3 * cl;
                        smem[(wv * 16 + cl) * 104 + 25 * p + v] = f32_to_bf16s(acc[mt][nt][r]);
                    }
                }
            }

        // GEMM2: M=16 (cl), N=32 (w), K=96 — reads own slab (compiler orders via lgkmcnt)
        f32x4 c0 = {0.f, 0.f, 0.f, 0.f}, c1 = {0.f, 0.f, 0.f, 0.f};
        #pragma unroll
        for (int s = 0; s < 3; ++s) {
            bf16x8 a2 = *(const bf16x8*)&smem[(wv * 16 + lcol) * 104 + 32 * s + 8 * q];
            c0 = __builtin_amdgcn_mfma_f32_16x16x32_bf16(a2, b2[0][s], c0, 0, 0, 0);
            c1 = __builtin_amdgcn_mfma_f32_16x16x32_bf16(a2, b2[1][s], c1, 0, 0, 0);
        }

        // Epilogue: BN + ReLU + residual + ReLU
        if (lg < 300) {
            #pragma unroll
            for (int nt = 0; nt < 2; ++nt) {
                int w = nt * 16 + lcol;
                if (w < 25) {
                    f32x4 cc = nt ? c1 : c0;
                    #pragma unroll
                    for (int r = 0; r < 4; ++r) {
                        int c = g * 16 + 4 * q + r;
                        float o = fmaxf(cc[r] * scs[c] + shs[c], 0.f);
                        out[outrow + (size_t)c * 7500 + w] = fmaxf(o + res[nt][r], 0.f);
                    }
                }
            }
        }
    }
}

extern "C" void kernel_launch(void* const* d_in, const int* in_sizes, int n_in,
                              void* d_out, int out_size, void* d_ws, size_t ws_size,
                              hipStream_t stream) {
    const float* x     = (const float*)d_in[0];
    const float* A     = (const float*)d_in[1];
    const float* W     = (const float*)d_in[2];
    const float* gamma = (const float*)d_in[3];
    const float* beta  = (const float*)d_in[4];
    const float* mean  = (const float*)d_in[5];
    const float* var   = (const float*)d_in[6];
    float* out = (float*)d_out;

    char* ws = (char*)d_ws;
    unsigned short* wt = (unsigned short*)ws;               // 24,576 B
    unsigned short* at = (unsigned short*)(ws + 24576);     // 6,144 B

    prep_kernel<<<60, 256, 0, stream>>>(A, W, wt, at);
    mega_kernel<<<dim3(38, 32), 512, 0, stream>>>(x, wt, at, gamma, beta, mean, var, out);
}

// Round 8
// 163.450 us; speedup vs baseline: 1.4847x; 1.4847x over previous
//
#include <hip/hip_runtime.h>
#include <cstdint>
#include <cstddef>

typedef short bf16x8 __attribute__((ext_vector_type(8)));
typedef float f32x4 __attribute__((ext_vector_type(4)));

#define EPS 1e-3f

__device__ __forceinline__ short f32_to_bf16s(float f) {
    union { float f; uint32_t u; } v; v.f = f;
    return (short)((v.u + 0x7FFFu + ((v.u >> 16) & 1u)) >> 16);
}

// K0: wt[kp][ci] = bf16(W[ci][kp]) (192x64); at[w][k] = bf16(A[p][v][w]) (32x96, k=p*25+v, zero-padded)
__global__ __launch_bounds__(256) void prep_kernel(const float* __restrict__ A,
                                                   const float* __restrict__ W,
                                                   unsigned short* __restrict__ wt,
                                                   unsigned short* __restrict__ at) {
    int idx = blockIdx.x * 256 + threadIdx.x;
    if (idx < 12288) {
        int kp = idx >> 6, ci = idx & 63;
        wt[idx] = (unsigned short)f32_to_bf16s(W[ci * 192 + kp]);
    } else {
        int j = idx - 12288;
        if (j < 3072) {
            int w = j / 96, k = j - w * 96;
            float val = 0.f;
            if (w < 25 && k < 75) {
                int p = k / 25, v = k - p * 25;
                val = A[(p * 25 + v) * 25 + w];
            }
            at[j] = (unsigned short)f32_to_bf16s(val);
        }
    }
}

// Mega: block = (l-chunk of 8, n), 512 threads; wave wv owns l = l0+wv end-to-end.
// LDS ALIASED: smem = xwL[8 qs][207 cols][8] (13248 sh) until b1 loaded,
//              then Ys[128][104] (13312 sh). Two barriers total.
// 27.1 KB LDS; launch_bounds(512,4): VGPR cap 128 (compiler ~56, no spill);
// runtime occupancy = 4 blocks/CU (thread-capped), 32 waves/CU.
__global__ __launch_bounds__(512, 4) void mega_kernel(
    const float* __restrict__ x,
    const unsigned short* __restrict__ wt,
    const unsigned short* __restrict__ at,
    const float* __restrict__ gamma, const float* __restrict__ beta,
    const float* __restrict__ mean, const float* __restrict__ var,
    float* __restrict__ out) {
    const int ch = blockIdx.x, n = blockIdx.y;
    const int l0 = ch * 8;
    const int tid = threadIdx.x;
    const int wv = tid >> 6, lane = tid & 63, q = lane >> 4, lcol = lane & 15;

    __shared__ __align__(16) short smem[13312];   // xwL (13248) then Ys (13312)
    __shared__ float scs[64], shs[64];

    // b2 fragments (at, L2-resident) + BN constants — prefetched before phase 1
    bf16x8 b2[2][3];
    #pragma unroll
    for (int nt = 0; nt < 2; ++nt)
        #pragma unroll
        for (int s = 0; s < 3; ++s)
            b2[nt][s] = *(const bf16x8*)(at + (size_t)(nt * 16 + lcol) * 96 + 32 * s + 8 * q);
    if (tid < 64) {
        float sc = gamma[tid] * rsqrtf(var[tid] + EPS);
        scs[tid] = sc;
        shs[tid] = beta[tid] - mean[tid] * sc;
    }

    // Phase 1: per-(ci,v) running 9-window over l = l0..l0+7 -> xwL (bf16)
    #pragma unroll 1
    for (int rep = 0; rep < 4; ++rep) {
        int cidx = tid + rep * 512;
        if (cidx < 1600) {
            int ci = cidx / 25, v = cidx - ci * 25;
            const float* xp = x + (size_t)(n * 64 + ci) * 7500 + v;
            float vals[16];
            #pragma unroll
            for (int i = 0; i < 16; ++i) {
                int l = l0 - 8 + i;
                vals[i] = (l >= 0 && l < 300) ? xp[l * 25] : 0.f;
            }
            float run = vals[0] + vals[1] + vals[2] + vals[3]
                      + vals[4] + vals[5] + vals[6] + vals[7];
            short* wb = &smem[(ci >> 3) * 1656 + (ci & 7)];
            #pragma unroll
            for (int j = 0; j < 8; ++j) {
                run += vals[j + 8];
                wb[(j * 25 + v) * 8] = f32_to_bf16s(run);
                run -= vals[j];
            }
        }
    }
    __syncthreads();   // barrier 1: xwL ready

    // b1 fragments: B[k=ci][col], cols wv*25 + nt*16 + lcol (<=206; cols>=200 are
    // stale-but-finite garbage whose D-columns map to w>=25 and are never stored)
    bf16x8 b1[2][2];
    #pragma unroll
    for (int nt = 0; nt < 2; ++nt) {
        int col = wv * 25 + nt * 16 + lcol;
        #pragma unroll
        for (int s = 0; s < 2; ++s)
            b1[nt][s] = *(const bf16x8*)&smem[(4 * s + q) * 1656 + col * 8];
    }
    __syncthreads();   // barrier 2: all xwL reads done; smem becomes Ys

    // Zero own Ys slab pad cols [72,104): wave-private from here on.
    #pragma unroll
    for (int i = lane; i < 512; i += 64) {
        int r = i >> 5, cc = 72 + (i & 31);
        smem[(wv * 16 + r) * 104 + cc] = 0;
    }

    const int lg = l0 + wv;
    const size_t outrow = ((size_t)n * 64 * 300 + lg) * 25;   // + c*7500 + w

    #pragma unroll 1
    for (int g = 0; g < 4; ++g) {
        // a1 fragments for this c-group (wt, L1/L2-resident)
        bf16x8 a1[3][2];
        #pragma unroll
        for (int mt = 0; mt < 3; ++mt)
            #pragma unroll
            for (int s = 0; s < 2; ++s)
                a1[mt][s] = *(const bf16x8*)(wt + (size_t)(g * 48 + mt * 16 + lcol) * 64 + 32 * s + 8 * q);

        // GEMM1: M=48 (kp of group g), N=32 (own l, v+pad), K=64
        f32x4 acc[3][2];
        #pragma unroll
        for (int mt = 0; mt < 3; ++mt)
            #pragma unroll
            for (int nt = 0; nt < 2; ++nt) acc[mt][nt] = (f32x4){0.f, 0.f, 0.f, 0.f};
        #pragma unroll
        for (int s = 0; s < 2; ++s)
            #pragma unroll
            for (int mt = 0; mt < 3; ++mt) {
                bf16x8 av = a1[mt][s];
                #pragma unroll
                for (int nt = 0; nt < 2; ++nt)
                    acc[mt][nt] = __builtin_amdgcn_mfma_f32_16x16x32_bf16(av, b1[nt][s], acc[mt][nt], 0, 0, 0);
            }

        // Residual prefetch (L2-hot: same rows fetched by phase 1 of this block)
        float res[2][4];
        #pragma unroll
        for (int nt = 0; nt < 2; ++nt) {
            int w = nt * 16 + lcol;
            bool val = (w < 25) && (lg < 300);
            #pragma unroll
            for (int r = 0; r < 4; ++r) {
                int c = g * 16 + 4 * q + r;
                res[nt][r] = val ? x[outrow + (size_t)c * 7500 + w] : 0.f;
            }
        }

        // Stage D -> own Ys slab rows (wv*16+cl), col 25p+v   (wave-private, no barrier)
        #pragma unroll
        for (int mt = 0; mt < 3; ++mt)
            #pragma unroll
            for (int nt = 0; nt < 2; ++nt) {
                int v = nt * 16 + lcol;
                if (v < 25) {
                    #pragma unroll
                    for (int r = 0; r < 4; ++r) {
                        int kpl = mt * 16 + 4 * q + r;
                        int cl = kpl / 3, p = kpl - 3 * cl;
                        smem[(wv * 16 + cl) * 104 + 25 * p + v] = f32_to_bf16s(acc[mt][nt][r]);
                    }
                }
            }

        // GEMM2: M=16 (cl), N=32 (w), K=96 — reads own slab (compiler orders via lgkmcnt)
        f32x4 c0 = {0.f, 0.f, 0.f, 0.f}, c1 = {0.f, 0.f, 0.f, 0.f};
        #pragma unroll
        for (int s = 0; s < 3; ++s) {
            bf16x8 a2 = *(const bf16x8*)&smem[(wv * 16 + lcol) * 104 + 32 * s + 8 * q];
            c0 = __builtin_amdgcn_mfma_f32_16x16x32_bf16(a2, b2[0][s], c0, 0, 0, 0);
            c1 = __builtin_amdgcn_mfma_f32_16x16x32_bf16(a2, b2[1][s], c1, 0, 0, 0);
        }

        // Epilogue: BN + ReLU + residual + ReLU
        if (lg < 300) {
            #pragma unroll
            for (int nt = 0; nt < 2; ++nt) {
                int w = nt * 16 + lcol;
                if (w < 25) {
                    f32x4 cc = nt ? c1 : c0;
                    #pragma unroll
                    for (int r = 0; r < 4; ++r) {
                        int c = g * 16 + 4 * q + r;
                        float o = fmaxf(cc[r] * scs[c] + shs[c], 0.f);
                        out[outrow + (size_t)c * 7500 + w] = fmaxf(o + res[nt][r], 0.f);
                    }
                }
            }
        }
    }
}

extern "C" void kernel_launch(void* const* d_in, const int* in_sizes, int n_in,
                              void* d_out, int out_size, void* d_ws, size_t ws_size,
                              hipStream_t stream) {
    const float* x     = (const float*)d_in[0];
    const float* A     = (const float*)d_in[1];
    const float* W     = (const float*)d_in[2];
    const float* gamma = (const float*)d_in[3];
    const float* beta  = (const float*)d_in[4];
    const float* mean  = (const float*)d_in[5];
    const float* var   = (const float*)d_in[6];
    float* out = (float*)d_out;

    char* ws = (char*)d_ws;
    unsigned short* wt = (unsigned short*)ws;               // 24,576 B
    unsigned short* at = (unsigned short*)(ws + 24576);     // 6,144 B

    prep_kernel<<<60, 256, 0, stream>>>(A, W, wt, at);
    mega_kernel<<<dim3(38, 32), 512, 0, stream>>>(x, wt, at, gamma, beta, mean, var, out);
}